// Round 5
// baseline (361.058 us; speedup 1.0000x reference)
//
#include <hip/hip_runtime.h>

typedef _Float16 f16;
typedef _Float16 f16x4 __attribute__((ext_vector_type(4)));
typedef _Float16 f16x8 __attribute__((ext_vector_type(8)));
typedef float f32x4 __attribute__((ext_vector_type(4)));
typedef float f32x16 __attribute__((ext_vector_type(16)));

#define MFMA16(a, b, c) __builtin_amdgcn_mfma_f32_16x16x32_f16(a, b, c, 0, 0, 0)
#define MFMA32(a, b, c) __builtin_amdgcn_mfma_f32_32x32x16_f16(a, b, c, 0, 0, 0)

// ---------------- Kernel 1: per-(tensor,b,c) mean / inv-std ----------------
__global__ __launch_bounds__(256) void stats_kernel(
    const float* __restrict__ content, const float* __restrict__ style,
    float* __restrict__ mu, float* __restrict__ rs)
{
    int bid = blockIdx.x;            // tensor*2048 + b*512 + c
    int tensor = bid >> 11;
    int row = bid & 2047;
    const float* src = (tensor ? style : content) + (size_t)row * 4096;
    int t = threadIdx.x;
    float s = 0.f, ss = 0.f;
    for (int i = t; i < 1024; i += 256) {
        float4 v = reinterpret_cast<const float4*>(src)[i];
        s  += v.x + v.y + v.z + v.w;
        ss += v.x * v.x + v.y * v.y + v.z * v.z + v.w * v.w;
    }
    for (int off = 32; off > 0; off >>= 1) {
        s  += __shfl_down(s, off);
        ss += __shfl_down(ss, off);
    }
    __shared__ float sb[4], ssb[4];
    int wv = t >> 6;
    if ((t & 63) == 0) { sb[wv] = s; ssb[wv] = ss; }
    __syncthreads();
    if (t == 0) {
        float S  = sb[0] + sb[1] + sb[2] + sb[3];
        float SS = ssb[0] + ssb[1] + ssb[2] + ssb[3];
        float m  = S * (1.f / 4096.f);
        float var = (SS - 4096.f * m * m) * (1.f / 4095.f);
        mu[bid] = m;
        rs[bid] = rsqrtf(var + 1e-5f);
    }
}

// ---------------- Kernel 2: fused norm + 1x1-conv (Q,K,V) -----------------
__global__ __launch_bounds__(256) void qkv_kernel(
    const float* __restrict__ content, const float* __restrict__ style,
    const float* __restrict__ Wq, const float* __restrict__ bq,
    const float* __restrict__ Wk, const float* __restrict__ bk,
    const float* __restrict__ Wv, const float* __restrict__ bv,
    const float* __restrict__ mu, const float* __restrict__ rs,
    f16* __restrict__ Qt, f16* __restrict__ Kt, f16* __restrict__ Vc)
{
    int z = blockIdx.z;
    int b = z / 3, p = z % 3;
    int n0 = blockIdx.x * 128;
    int o0 = blockIdx.y * 128;
    const float* X    = (p == 0 ? content : style) + (size_t)b * 512 * 4096;
    const float* W    = (p == 0 ? Wq : (p == 1 ? Wk : Wv));
    const float* bias = (p == 0 ? bq : (p == 1 ? bk : bv));
    const float* muT = mu + (p == 0 ? 0 : 2048) + b * 512;
    const float* rsT = rs + (p == 0 ? 0 : 2048) + b * 512;
    bool norm = (p < 2);

    __shared__ __align__(16) f16 Xt[128][40];
    __shared__ __align__(16) f16 Wl[128][40];

    int t = threadIdx.x;
    int lane = t & 63, w = t >> 6;
    int wn = (w & 1) * 64, wo = (w >> 1) * 64;
    int lg = lane >> 4, li = lane & 15;

    f32x4 acc[4][4];
#pragma unroll
    for (int i = 0; i < 4; ++i)
#pragma unroll
        for (int j = 0; j < 4; ++j)
#pragma unroll
            for (int e = 0; e < 4; ++e) acc[i][j][e] = 0.f;

    for (int kk = 0; kk < 16; ++kk) {
        int c0 = kk * 32;
        __syncthreads();
#pragma unroll
        for (int r = 0; r < 4; ++r) {
            int linear = r * 256 + t;
            int c  = linear >> 5;
            int nq = linear & 31;
            float4 v = reinterpret_cast<const float4*>(X + (size_t)(c0 + c) * 4096 + n0)[nq];
            float m = 0.f, sc = 1.f;
            if (norm) { m = muT[c0 + c]; sc = rsT[c0 + c]; }
            int n = nq * 4;
            Xt[n + 0][c] = (f16)((v.x - m) * sc);
            Xt[n + 1][c] = (f16)((v.y - m) * sc);
            Xt[n + 2][c] = (f16)((v.z - m) * sc);
            Xt[n + 3][c] = (f16)((v.w - m) * sc);
        }
#pragma unroll
        for (int r = 0; r < 4; ++r) {
            int linear = r * 256 + t;
            int o  = linear >> 3;
            int cq = linear & 7;
            float4 v = reinterpret_cast<const float4*>(W + (size_t)(o0 + o) * 512 + c0)[cq];
            int c = cq * 4;
            Wl[o][c + 0] = (f16)v.x;
            Wl[o][c + 1] = (f16)v.y;
            Wl[o][c + 2] = (f16)v.z;
            Wl[o][c + 3] = (f16)v.w;
        }
        __syncthreads();

        f16x8 xf[4], wf[4];
#pragma unroll
        for (int f = 0; f < 4; ++f) {
            xf[f] = *reinterpret_cast<const f16x8*>(&Xt[wn + f * 16 + li][lg * 8]);
            wf[f] = *reinterpret_cast<const f16x8*>(&Wl[wo + f * 16 + li][lg * 8]);
        }
        if (p < 2) {
#pragma unroll
            for (int i = 0; i < 4; ++i)
#pragma unroll
                for (int j = 0; j < 4; ++j)
                    acc[i][j] = MFMA16(xf[i], wf[j], acc[i][j]);
        } else {
#pragma unroll
            for (int i = 0; i < 4; ++i)
#pragma unroll
                for (int j = 0; j < 4; ++j)
                    acc[i][j] = MFMA16(wf[i], xf[j], acc[i][j]);
        }
    }

    if (p < 2) {
        f16* dst = (p == 0 ? Qt : Kt) + (size_t)b * 4096 * 512;
#pragma unroll
        for (int j = 0; j < 4; ++j) {
            int o = o0 + wo + j * 16 + li;
            float bb = bias[o];
#pragma unroll
            for (int i = 0; i < 4; ++i)
#pragma unroll
                for (int e = 0; e < 4; ++e) {
                    int n = n0 + wn + i * 16 + lg * 4 + e;
                    dst[(size_t)n * 512 + o] = (f16)(acc[i][j][e] + bb);
                }
        }
    } else {
#pragma unroll
        for (int i = 0; i < 4; ++i)
#pragma unroll
            for (int e = 0; e < 4; ++e) {
                int o = o0 + wo + i * 16 + lg * 4 + e;
                float bb = bias[o];
#pragma unroll
                for (int j = 0; j < 4; ++j) {
                    int n = n0 + wn + j * 16 + li;
                    Vc[((size_t)b * 512 + o) * 4096 + n] = (f16)(acc[i][j][e] + bb);
                }
            }
    }
}

// ---------------- Kernel 3: flash attention, producer/consumer, 32x32 QK ---
// 512 thr = 4 QK waves (w0-3: h=w>>1 m-half, j=w&1 q-half) + 4 PV waves.
// Per iter: Phase1 = QK MFMA(it) + K-stage(it+1) || PV MFMA(it-1); barrier;
//           Phase2 = QK softmax(it) (cross-wave max via LDS) || PV V-load(it); barrier.
__global__ __launch_bounds__(512, 2) void attn_kernel(
    const f16* __restrict__ Qt, const f16* __restrict__ Kt,
    const f16* __restrict__ Vc, float* __restrict__ out)
{
    int bid = blockIdx.x;
    int orig = (bid & 7) * 32 + (bid >> 3);   // XCD chunking
    int b = orig >> 6;
    int n0 = (orig & 63) * 64;

    int t = threadIdx.x;
    int lane = t & 63, w = t >> 6;
    int lg = lane >> 4, li = lane & 15;
    int li32 = lane & 31, hi = lane >> 5;

    __shared__ __align__(16) f16 Km[2][64][520];   // K ping-pong [m][c], row data = 1024B
    __shared__ __align__(16) f16 Pl[2][64][72];    // P ping-pong [n(q)][m]
    __shared__ __align__(16) float Rrow[2][64];
    __shared__ __align__(16) float Lrow[64];
    __shared__ float pmx [2][2][2][32];            // [ping][h][j][q]
    __shared__ float psum[2][2][2][32];
    __shared__ int   Rflag[2][2];

    const f16* Qb = Qt + (size_t)b * 4096 * 512;
    const f16* Kb = Kt + (size_t)b * 4096 * 512;
    const f16* Vb = Vc + (size_t)b * 512 * 4096;

    if (w < 4) {
        // =============== QK / softmax wave (h = m-half, j = q-half) ========
        int h = w >> 1, j = w & 1;

        // Q strip: 32 q-cols (j*32..+32), full c=512, B-frag layout
        f16x8 qf[32];
#pragma unroll
        for (int kk = 0; kk < 32; ++kk)
            qf[kk] = *reinterpret_cast<const f16x8*>(
                Qb + (size_t)(n0 + j * 32 + li32) * 512 + kk * 16 + hi * 8);

#define STAGEK(TILE)                                                           \
        {                                                                      \
            int _dbuf = (TILE) & 1;                                            \
            _Pragma("unroll")                                                  \
            for (int r = 0; r < 16; ++r) {                                     \
                const f16* _gs = Kb + ((size_t)(TILE) * 64 + w * 16 + r) * 512 \
                                 + lane * 8;                                   \
                __builtin_amdgcn_global_load_lds(                              \
                    (const __attribute__((address_space(1))) void*)_gs,        \
                    (__attribute__((address_space(3))) void*)&Km[_dbuf][w * 16 + r][0], \
                    16, 0, 0);                                                 \
            }                                                                  \
        }

        STAGEK(0);
        float Mreg = -3.4e38f, Lreg = 0.f, r_prev = 1.f;
        __syncthreads();   // prologue barrier (K0 drained by waitcnt before barrier)

        for (int it = 0; it <= 64; ++it) {
            int cur = it & 1;
            f32x16 s;
            float mx = -3.4e38f;
            // ---------------- Phase 1 ----------------
            if (it < 63) STAGEK(it + 1);
            if (it < 64) {
                f32x16 sa, sb;
#pragma unroll
                for (int e = 0; e < 16; ++e) { sa[e] = 0.f; sb[e] = 0.f; }
                __builtin_amdgcn_s_setprio(1);
#pragma unroll
                for (int kk = 0; kk < 32; kk += 2) {
                    f16x8 k0 = *reinterpret_cast<const f16x8*>(
                        &Km[cur][h * 32 + li32][kk * 16 + hi * 8]);
                    f16x8 k1 = *reinterpret_cast<const f16x8*>(
                        &Km[cur][h * 32 + li32][(kk + 1) * 16 + hi * 8]);
                    sa = MFMA32(k0, qf[kk], sa);
                    sb = MFMA32(k1, qf[kk + 1], sb);
                }
                __builtin_amdgcn_s_setprio(0);
#pragma unroll
                for (int e = 0; e < 16; ++e) s[e] = sa[e] + sb[e];
                mx = s[0];
#pragma unroll
                for (int e = 1; e < 16; ++e) mx = fmaxf(mx, s[e]);
                mx = fmaxf(mx, __shfl_xor(mx, 32));
                if (lane < 32) pmx[cur][h][j][lane] = mx;
            }
            __syncthreads();   // bar A
            // ---------------- Phase 2 ----------------
            if (it >= 1) {     // lagged L-update for tile it-1
                int pb = (it - 1) & 1;
                float ps = psum[pb][0][j][li32] + psum[pb][1][j][li32];
                Lreg = Lreg * r_prev + ps;
            }
            if (it < 64) {
                float oth = pmx[cur][h ^ 1][j][li32];
                float mx2 = fmaxf(mx, oth);
                bool needR = (mx2 - Mreg) > 4.0f;      // defer-max THR=4
                float Mnew = needR ? mx2 : Mreg;
                float r = needR ? __expf(Mreg - Mnew) : 1.f;
                Mreg = Mnew;
                r_prev = r;
                float p[16];
                float sum = 0.f;
#pragma unroll
                for (int e = 0; e < 16; ++e) {
                    p[e] = __expf(s[e] - Mnew);
                    sum += p[e];
                }
                sum += __shfl_xor(sum, 32);
                if (lane < 32) psum[cur][h][j][lane] = sum;
                // P -> LDS: rows q = j*32+li32; m = h*32 + 8g + 4hi + e
#pragma unroll
                for (int g = 0; g < 4; ++g) {
                    f16x4 pk;
#pragma unroll
                    for (int e = 0; e < 4; ++e) pk[e] = (f16)p[g * 4 + e];
                    *reinterpret_cast<f16x4*>(
                        &Pl[cur][j * 32 + li32][h * 32 + g * 8 + hi * 4]) = pk;
                }
                if (h == 0 && lane < 32) Rrow[cur][j * 32 + lane] = r;
                int any = __any(needR);
                if (h == 0 && lane == 0) Rflag[cur][j] = any;
            }
            if (it == 64 && h == 0 && lane < 32) Lrow[j * 32 + lane] = Lreg;
            __syncthreads();   // bar B
        }
#undef STAGEK
    } else {
        // =============== PV wave ===============
        int pw = w - 4;
        int c0 = pw * 128;
        f32x4 acc[4][8];
#pragma unroll
        for (int fn = 0; fn < 4; ++fn)
#pragma unroll
            for (int fc = 0; fc < 8; ++fc)
#pragma unroll
                for (int e = 0; e < 4; ++e) acc[fn][fc][e] = 0.f;
        f16x8 vfr[8][2];   // V frags for tile (it-1)

        __syncthreads();   // prologue barrier

        for (int it = 0; it <= 64; ++it) {
            // ---------------- Phase 1: PV MFMA for tile it-1 ----------------
            if (it >= 1) {
                int pp = (it - 1) & 1;
                int flag = Rflag[pp][0] | Rflag[pp][1];
                if (flag) {
#pragma unroll
                    for (int fn = 0; fn < 4; ++fn) {
                        f32x4 rv = *reinterpret_cast<const f32x4*>(&Rrow[pp][fn * 16 + lg * 4]);
#pragma unroll
                        for (int fc = 0; fc < 8; ++fc)
#pragma unroll
                            for (int e = 0; e < 4; ++e) acc[fn][fc][e] *= rv[e];
                    }
                }
                __builtin_amdgcn_s_setprio(1);
#pragma unroll
                for (int fn = 0; fn < 4; ++fn) {
                    f16x8 af0 = *reinterpret_cast<const f16x8*>(&Pl[pp][fn * 16 + li][lg * 8]);
                    f16x8 af1 = *reinterpret_cast<const f16x8*>(&Pl[pp][fn * 16 + li][32 + lg * 8]);
#pragma unroll
                    for (int fc = 0; fc < 8; ++fc) {
                        acc[fn][fc] = MFMA16(af0, vfr[fc][0], acc[fn][fc]);
                        acc[fn][fc] = MFMA16(af1, vfr[fc][1], acc[fn][fc]);
                    }
                }
                __builtin_amdgcn_s_setprio(0);
            }
            __syncthreads();   // bar A
            // ---------------- Phase 2: V loads for tile it ----------------
            if (it < 64) {
                const f16* vs = Vb + (size_t)(c0 + li) * 4096 + it * 64 + lg * 8;
#pragma unroll
                for (int fc = 0; fc < 8; ++fc) {
                    vfr[fc][0] = *reinterpret_cast<const f16x8*>(vs + (size_t)fc * 16 * 4096);
                    vfr[fc][1] = *reinterpret_cast<const f16x8*>(vs + (size_t)fc * 16 * 4096 + 32);
                }
            }
            __syncthreads();   // bar B
        }

        // epilogue: divide by L, store out[b][c][n]
        float* ob = out + (size_t)b * 512 * 4096;
#pragma unroll
        for (int fn = 0; fn < 4; ++fn) {
            f32x4 lv = *reinterpret_cast<const f32x4*>(&Lrow[fn * 16 + lg * 4]);
            f32x4 linv;
#pragma unroll
            for (int e = 0; e < 4; ++e) linv[e] = 1.f / lv[e];
#pragma unroll
            for (int fc = 0; fc < 8; ++fc) {
                int c = c0 + fc * 16 + li;
                f32x4 o4;
#pragma unroll
                for (int e = 0; e < 4; ++e) o4[e] = acc[fn][fc][e] * linv[e];
                *reinterpret_cast<f32x4*>(ob + (size_t)c * 4096 + n0 + fn * 16 + lg * 4) = o4;
            }
        }
    }
}

// ---------------------------------------------------------------------------
extern "C" void kernel_launch(void* const* d_in, const int* in_sizes, int n_in,
                              void* d_out, int out_size, void* d_ws, size_t ws_size,
                              hipStream_t stream)
{
    const float* content = (const float*)d_in[0];
    const float* style   = (const float*)d_in[1];
    const float* Wq = (const float*)d_in[2];
    const float* bq = (const float*)d_in[3];
    const float* Wk = (const float*)d_in[4];
    const float* bk = (const float*)d_in[5];
    const float* Wv = (const float*)d_in[6];
    const float* bv = (const float*)d_in[7];
    float* out = (float*)d_out;

    const size_t TEN = (size_t)4 * 4096 * 512;
    f16* Qt = (f16*)d_ws;
    f16* Kt = Qt + TEN;
    f16* Vc = Kt + TEN;
    float* mu = (float*)(Vc + TEN);
    float* rs = mu + 4096;

    hipLaunchKernelGGL(stats_kernel, dim3(4096), dim3(256), 0, stream,
                       content, style, mu, rs);
    hipLaunchKernelGGL(qkv_kernel, dim3(32, 4, 12), dim3(256), 0, stream,
                       content, style, Wq, bq, Wk, bk, Wv, bv, mu, rs, Qt, Kt, Vc);
    hipLaunchKernelGGL(attn_kernel, dim3(256), dim3(512), 0, stream,
                       Qt, Kt, Vc, out);
}